// Round 1
// baseline (5340.404 us; speedup 1.0000x reference)
//
#include <hip/hip_runtime.h>
#include <cstddef>

// LinearAttention on MI355X, round 1: all-fp32 vector, fused structure.
// y = LN( U_b @ softmax_d(W_q X_b) + b_out ),  U_b = scale * W_out ctx_b^T (per head)
// ctx_b[h,d,e] = (sum_n exp(K[d,n]) V[e,n]) / (Z_d * 4096)   (softmax_n unnormalized + Z)
//
// ws usage (floats): Cp 16.78M + Zp 0.26M + ctx 0.52M + U 2.10M  = 19,660,800 f = 78.6 MB

#define NB   16
#define CIN  256
#define NTOK 4096
#define SEGS 32

#define CP_SZ   (NB*SEGS*32768)
#define ZP_OFF  (CP_SZ)
#define ZP_SZ   (NB*SEGS*512)
#define CTX_OFF (ZP_OFF + ZP_SZ)
#define CTX_SZ  (NB*32768)
#define U_OFF   (CTX_OFF + CTX_SZ)

// ---------------- Kernel A: KV-GEMM + exp + partial context -----------------
// grid (SEGS, NB), 256 thr. Each block: 128 tokens (4 tiles of 32).
// LDS: xt[256][32] | wT[32][132] | ke[64][36] | vT[32][68]  = 16896 f = 67584 B
__global__ __launch_bounds__(256, 2)
void kvctx_kernel(const float* __restrict__ x, const float* __restrict__ wqkv,
                  float* __restrict__ Cp, float* __restrict__ Zp)
{
    extern __shared__ float sm[];
    float* xt = sm;                       // [256][32]
    float* wT = sm + 8192;                // [32][132]
    float* ke = sm + 8192 + 4224;         // [64][36]  exp(K) tile
    float* vT = sm + 8192 + 4224 + 2304;  // [32][68]  V tile transposed [n][e]

    const int tid = threadIdx.x;
    const int seg = blockIdx.x;
    const int b   = blockIdx.y;

    const int row8  = tid >> 5;       // 0..7
    const int col32 = tid & 31;
    const int r0 = (tid >> 3) << 2;   // GEMM out rows 0..124
    const int c0 = (tid & 7) << 2;    // GEMM out cols 0..28
    const int d0 = (tid >> 4) << 2;   // C' rows 0..60
    const int e0 = (tid & 15) << 2;   // C' cols 0..60

    float accC[8][4][4];
    float zacc[8];
    #pragma unroll
    for (int h = 0; h < 8; ++h) {
        zacc[h] = 0.f;
        #pragma unroll
        for (int i = 0; i < 4; ++i)
            #pragma unroll
            for (int j = 0; j < 4; ++j) accC[h][i][j] = 0.f;
    }

    for (int t = 0; t < 4; ++t) {
        const int n0 = seg * 128 + t * 32;
        const float* xb = x + (size_t)b * CIN * NTOK + n0;
        __syncthreads();
        #pragma unroll
        for (int it = 0; it < 32; ++it) {
            int row = it * 8 + row8;
            xt[row * 32 + col32] = xb[(size_t)row * NTOK + col32];
        }
        __syncthreads();

        #pragma unroll
        for (int h = 0; h < 8; ++h) {
            float acc[4][4];
            #pragma unroll
            for (int i = 0; i < 4; ++i)
                #pragma unroll
                for (int j = 0; j < 4; ++j) acc[i][j] = 0.f;

            for (int kc = 0; kc < 8; ++kc) {
                // stage wT[kk][r]: 128 rows (K then V of head h), 32 k's
                #pragma unroll
                for (int ir = 0; ir < 16; ++ir) {
                    int r = ir * 8 + row8;
                    int o = (r < 64) ? (512 + h * 64 + r) : (1024 + h * 64 + (r - 64));
                    wT[col32 * 132 + r] = wqkv[o * 256 + kc * 32 + col32];
                }
                __syncthreads();
                #pragma unroll 4
                for (int kk = 0; kk < 32; ++kk) {
                    float4 wv = *(const float4*)&wT[kk * 132 + r0];
                    float4 xv = *(const float4*)&xt[(kc * 32 + kk) * 32 + c0];
                    acc[0][0] += wv.x*xv.x; acc[0][1] += wv.x*xv.y; acc[0][2] += wv.x*xv.z; acc[0][3] += wv.x*xv.w;
                    acc[1][0] += wv.y*xv.x; acc[1][1] += wv.y*xv.y; acc[1][2] += wv.y*xv.z; acc[1][3] += wv.y*xv.w;
                    acc[2][0] += wv.z*xv.x; acc[2][1] += wv.z*xv.y; acc[2][2] += wv.z*xv.z; acc[2][3] += wv.z*xv.w;
                    acc[3][0] += wv.w*xv.x; acc[3][1] += wv.w*xv.y; acc[3][2] += wv.w*xv.z; acc[3][3] += wv.w*xv.w;
                }
                __syncthreads();
            }

            if (r0 < 64) {   // K rows -> exp, store
                #pragma unroll
                for (int i = 0; i < 4; ++i) {
                    float4 ev;
                    ev.x = expf(acc[i][0]); ev.y = expf(acc[i][1]);
                    ev.z = expf(acc[i][2]); ev.w = expf(acc[i][3]);
                    *(float4*)&ke[(r0 + i) * 36 + c0] = ev;
                }
            } else {          // V rows -> store transposed [n][e]
                #pragma unroll
                for (int i = 0; i < 4; ++i)
                    #pragma unroll
                    for (int j = 0; j < 4; ++j)
                        vT[(c0 + j) * 68 + (r0 - 64 + i)] = acc[i][j];
            }
            __syncthreads();

            if (tid < 64) {   // Z partial for this head/tile
                float zs = 0.f;
                #pragma unroll
                for (int j4 = 0; j4 < 8; ++j4) {
                    float4 kv4 = *(const float4*)&ke[tid * 36 + j4 * 4];
                    zs += kv4.x + kv4.y + kv4.z + kv4.w;
                }
                zacc[h] += zs;
            }

            // C'[d,e] += sum_n expK[d,n] * V[e,n]
            for (int j4 = 0; j4 < 8; ++j4) {
                float ek[4][4], vv[4][4];
                #pragma unroll
                for (int i = 0; i < 4; ++i) {
                    float4 e4 = *(const float4*)&ke[(d0 + i) * 36 + j4 * 4];
                    ek[i][0] = e4.x; ek[i][1] = e4.y; ek[i][2] = e4.z; ek[i][3] = e4.w;
                }
                #pragma unroll
                for (int s = 0; s < 4; ++s) {
                    float4 v4 = *(const float4*)&vT[(j4 * 4 + s) * 68 + e0];
                    vv[s][0] = v4.x; vv[s][1] = v4.y; vv[s][2] = v4.z; vv[s][3] = v4.w;
                }
                #pragma unroll
                for (int s = 0; s < 4; ++s)
                    #pragma unroll
                    for (int i = 0; i < 4; ++i)
                        #pragma unroll
                        for (int j = 0; j < 4; ++j)
                            accC[h][i][j] += ek[i][s] * vv[s][j];
            }
        }
    }

    float* cpb = Cp + (size_t)(b * SEGS + seg) * 32768;
    #pragma unroll
    for (int h = 0; h < 8; ++h)
        #pragma unroll
        for (int i = 0; i < 4; ++i) {
            float4 v4 = make_float4(accC[h][i][0], accC[h][i][1], accC[h][i][2], accC[h][i][3]);
            *(float4*)&cpb[h * 4096 + (d0 + i) * 64 + e0] = v4;
        }
    if (tid < 64) {
        float* zpb = Zp + (size_t)(b * SEGS + seg) * 512;
        #pragma unroll
        for (int h = 0; h < 8; ++h) zpb[h * 64 + tid] = zacc[h];
    }
}

// ---------------- Kernel B0: reduce partials -> normalized ctx --------------
__global__ void bctx_kernel(const float* __restrict__ Cp, const float* __restrict__ Zp,
                            float* __restrict__ ctx)
{
    int gid = blockIdx.x * 256 + threadIdx.x;   // 16 * 32768 total
    int b = gid >> 15;
    int r = gid & 32767;
    int hd = r >> 6;
    float cs = 0.f, zs = 0.f;
    for (int s = 0; s < SEGS; ++s) {
        cs += Cp[(size_t)(b * SEGS + s) * 32768 + r];
        zs += Zp[(b * SEGS + s) * 512 + hd];
    }
    ctx[(size_t)b * 32768 + r] = cs / (zs * 4096.f);
}

// ---------------- Kernel B1: U = scale * W_out ctx^T (per head) -------------
// grid (8, NB), 256 thr
__global__ void uprep_kernel(const float* __restrict__ wout, const float* __restrict__ ctx,
                             float* __restrict__ U)
{
    __shared__ float cl[64 * 65];
    const int h = blockIdx.x, b = blockIdx.y, tid = threadIdx.x;
    const float* cb = ctx + (size_t)b * 32768 + h * 4096;
    #pragma unroll
    for (int it = 0; it < 16; ++it) {
        int idx = it * 256 + tid;
        cl[(idx >> 6) * 65 + (idx & 63)] = cb[idx];
    }
    __syncthreads();
    const int d = tid & 63, og = tid >> 6;
    float* ub = U + (size_t)b * 131072;
    for (int k = 0; k < 64; ++k) {
        int o = og * 64 + k;
        const float* wrow = wout + o * 512 + h * 64;
        float s = 0.f;
        #pragma unroll
        for (int e = 0; e < 64; ++e) s += wrow[e] * cl[d * 65 + e];
        ub[o * 512 + h * 64 + d] = s * 0.125f;   // scale = DIM_HEAD^-0.5
    }
}

// ---------------- Kernel C: q-GEMM -> softmax_d -> U-GEMM -> bias -> LN -----
// grid (128, NB), 256 thr, 32 tokens/block.
// LDS: region0 16384 f (xt[256][32]+wT[16][512] -> qsm[512][32] -> ylds/red)
//      region1  4096 f (uT[16][256], xor-swizzled)      total 20480 f = 81920 B
__global__ __launch_bounds__(256, 2)
void qout_kernel(const float* __restrict__ x, const float* __restrict__ wqkv,
                 const float* __restrict__ U, const float* __restrict__ bout,
                 const float* __restrict__ gg, float* __restrict__ out)
{
    extern __shared__ float sm[];
    float* xt    = sm;            // [256][32]
    float* wT    = sm + 8192;     // [16][512] swizzled
    float* qsm   = sm;            // [512][32] (aliases xt+wT after barrier)
    float* uT    = sm + 16384;    // [16][256] swizzled
    float* ylds  = sm;            // [256][36]
    float* red   = sm + 9216;     // [256]
    float* meanl = sm + 9472;     // [32]
    float* invl  = sm + 9504;     // [32]

    const int tid = threadIdx.x;
    const int b  = blockIdx.y;
    const int n0 = blockIdx.x * 32;
    const int row8 = tid >> 5, col32 = tid & 31;

    const float* xb = x + (size_t)b * CIN * NTOK + n0;
    #pragma unroll
    for (int it = 0; it < 32; ++it) {
        int row = it * 8 + row8;
        xt[row * 32 + col32] = xb[(size_t)row * NTOK + col32];
    }

    // ---- q GEMM: thread owns head h = tid>>5, token col = tid&31, all 64 d
    const int h = tid >> 5;
    const int col = tid & 31;
    float qa[64];
    #pragma unroll
    for (int d = 0; d < 64; ++d) qa[d] = 0.f;

    const int kks = tid & 15;
    const int rb  = tid >> 4;
    for (int kc = 0; kc < 16; ++kc) {
        __syncthreads();
        #pragma unroll
        for (int it = 0; it < 32; ++it) {
            int r = it * 16 + rb;
            wT[kks * 512 + (r ^ ((kks & 7) << 2))] = wqkv[r * 256 + kc * 16 + kks];
        }
        __syncthreads();
        for (int kk = 0; kk < 16; ++kk) {
            float xs = xt[(kc * 16 + kk) * 32 + col];
            const int sw = (kk & 7) << 2;
            #pragma unroll
            for (int d4 = 0; d4 < 16; ++d4) {
                float4 w4 = *(const float4*)&wT[kk * 512 + ((h * 64 + d4 * 4) ^ sw)];
                qa[4*d4+0] += w4.x * xs;
                qa[4*d4+1] += w4.y * xs;
                qa[4*d4+2] += w4.z * xs;
                qa[4*d4+3] += w4.w * xs;
            }
        }
    }

    // ---- softmax over d (in registers)
    float m = qa[0];
    #pragma unroll
    for (int d = 1; d < 64; ++d) m = fmaxf(m, qa[d]);
    float s = 0.f;
    #pragma unroll
    for (int d = 0; d < 64; ++d) { qa[d] = expf(qa[d] - m); s += qa[d]; }
    float rs = 1.f / s;
    __syncthreads();   // xt/wT dead after this point
    #pragma unroll
    for (int d = 0; d < 64; ++d) qsm[(h * 64 + d) * 32 + col] = qa[d] * rs;

    // ---- y = U @ qsm
    const int yr0 = (tid >> 3) << 3;   // 0..248
    const int yc0 = (tid & 7) << 2;    // 0..28
    float ya[8][4];
    #pragma unroll
    for (int i = 0; i < 8; ++i)
        #pragma unroll
        for (int j = 0; j < 4; ++j) ya[i][j] = 0.f;

    const float* Ub = U + (size_t)b * 131072;
    for (int uc = 0; uc < 32; ++uc) {
        __syncthreads();
        #pragma unroll
        for (int it = 0; it < 16; ++it) {
            int r = it * 16 + rb;
            uT[kks * 256 + (r ^ ((kks & 7) << 2))] = Ub[r * 512 + uc * 16 + kks];
        }
        __syncthreads();
        for (int kk = 0; kk < 16; ++kk) {
            const int sw = (kk & 7) << 2;
            float4 u1 = *(const float4*)&uT[kk * 256 + (yr0 ^ sw)];
            float4 u2 = *(const float4*)&uT[kk * 256 + ((yr0 + 4) ^ sw)];
            float4 q4 = *(const float4*)&qsm[(uc * 16 + kk) * 32 + yc0];
            float ur[8] = {u1.x,u1.y,u1.z,u1.w,u2.x,u2.y,u2.z,u2.w};
            float qr[4] = {q4.x,q4.y,q4.z,q4.w};
            #pragma unroll
            for (int i = 0; i < 8; ++i)
                #pragma unroll
                for (int j = 0; j < 4; ++j)
                    ya[i][j] += ur[i] * qr[j];
        }
    }
    #pragma unroll
    for (int i = 0; i < 8; ++i) {
        float bo = bout[yr0 + i];
        #pragma unroll
        for (int j = 0; j < 4; ++j) ya[i][j] += bo;
    }
    __syncthreads();   // qsm / uT reads done
    #pragma unroll
    for (int i = 0; i < 8; ++i)
        *(float4*)&ylds[(yr0 + i) * 36 + yc0] = make_float4(ya[i][0], ya[i][1], ya[i][2], ya[i][3]);
    __syncthreads();

    // ---- LayerNorm over 256 channels, two-pass (matches reference)
    const int lc = tid & 31, lg = tid >> 5;
    float sa = 0.f;
    #pragma unroll
    for (int i = 0; i < 32; ++i) sa += ylds[(lg * 32 + i) * 36 + lc];
    red[lg * 32 + lc] = sa;
    __syncthreads();
    if (tid < 32) {
        float mt = 0.f;
        #pragma unroll
        for (int g8 = 0; g8 < 8; ++g8) mt += red[g8 * 32 + tid];
        meanl[tid] = mt * (1.f / 256.f);
    }
    __syncthreads();
    float mm = meanl[lc];
    float sq = 0.f;
    #pragma unroll
    for (int i = 0; i < 32; ++i) { float dv = ylds[(lg * 32 + i) * 36 + lc] - mm; sq += dv * dv; }
    red[lg * 32 + lc] = sq;
    __syncthreads();
    if (tid < 32) {
        float vt = 0.f;
        #pragma unroll
        for (int g8 = 0; g8 < 8; ++g8) vt += red[g8 * 32 + tid];
        invl[tid] = rsqrtf(vt * (1.f / 256.f) + 1e-5f);
    }
    __syncthreads();
    float* ob = out + (size_t)b * CIN * NTOK + n0;
    float iv = invl[lc];
    mm = meanl[lc];
    #pragma unroll
    for (int it = 0; it < 32; ++it) {
        int o = it * 8 + lg;
        float val = (ylds[o * 36 + lc] - mm) * iv * gg[o];
        ob[(size_t)o * NTOK + lc] = val;
    }
}

// ----------------------------------------------------------------------------
extern "C" void kernel_launch(void* const* d_in, const int* in_sizes, int n_in,
                              void* d_out, int out_size, void* d_ws, size_t ws_size,
                              hipStream_t stream)
{
    const float* x    = (const float*)d_in[0];
    const float* wqkv = (const float*)d_in[1];
    const float* wout = (const float*)d_in[2];
    const float* bout = (const float*)d_in[3];
    const float* g    = (const float*)d_in[4];
    float* out = (float*)d_out;

    float* ws  = (float*)d_ws;
    float* Cp  = ws;
    float* Zp  = ws + ZP_OFF;
    float* ctx = ws + CTX_OFF;
    float* U   = ws + U_OFF;

    hipLaunchKernelGGL(kvctx_kernel, dim3(SEGS, NB), dim3(256), 67584, stream, x, wqkv, Cp, Zp);
    hipLaunchKernelGGL(bctx_kernel,  dim3(2048),     dim3(256), 0,     stream, Cp, Zp, ctx);
    hipLaunchKernelGGL(uprep_kernel, dim3(8, NB),    dim3(256), 0,     stream, wout, ctx, U);
    hipLaunchKernelGGL(qout_kernel,  dim3(128, NB),  dim3(256), 81920, stream, x, wqkv, U, bout, g, out);
}

// Round 3
// 208.488 us; speedup vs baseline: 25.6149x; 25.6149x over previous
//
#include <hip/hip_runtime.h>
#include <cstddef>
#include <cstdint>

// LinearAttention MI355X round 3: round-2 bf16-MFMA structure with the XT
// stride bug fixed (b*1048576 shorts per batch, was b*2097152 = OOB + race).
//
// y = LN( U_b @ softmax_d(W_q X_b) + b_out ),  U_b = 0.125 * W_out ctx_b^T (per head)
// ctx_b[h,d,e] = (sum_n exp(K[d,n]) V[e,n]) / (Z_d * 4096)
//
// ws layout (bytes):
//   XTs  (bf16, swizzled [b][n][c]) : 0          .. 33,554,432
//   wbf  (bf16 wqkv)                : 33,554,432 .. 34,340,864
//   Ubf  (bf16 U)                   : 34,340,864 .. 38,535,168
//   Cp   (f32 ctx partials)         : 38,535,168 .. 46,923,776
//   Zp   (f32 Z partials)           : 46,923,776 .. 47,054,848
//   ctx  (f32)                      : 47,054,848 .. 49,152,000

typedef __attribute__((ext_vector_type(8))) short s16x8;
typedef __attribute__((ext_vector_type(4))) float f32x4;

#define MFMA(a,b,c) __builtin_amdgcn_mfma_f32_16x16x32_bf16(a,b,c,0,0,0)

#define XT_BSTRIDE 1048576   // shorts per batch: 4096 tokens * 256 ch

__device__ __forceinline__ unsigned short f2bf(float f){
    union { float f; unsigned int u; } v; v.f = f;
    unsigned int u = v.u;
    unsigned int r = (u + 0x7FFFu + ((u >> 16) & 1u)) >> 16;   // RNE
    return (unsigned short)r;
}
__device__ __forceinline__ float bf2f(unsigned short b){
    union { unsigned int u; float f; } v; v.u = ((unsigned int)b) << 16;
    return v.f;
}
__device__ __forceinline__ void gload_lds16(const void* g, void* l){
    __builtin_amdgcn_global_load_lds(
        (const __attribute__((address_space(1))) unsigned int*)g,
        (__attribute__((address_space(3))) unsigned int*)l, 16, 0, 0);
}

// ------------- prep: x [b][c][n] f32 -> XT [b][n][c] bf16, block-swizzled ----
__global__ __launch_bounds__(256)
void xprep_kernel(const float* __restrict__ x, unsigned short* __restrict__ XT)
{
    __shared__ float xt[64*68];
    const int tid = threadIdx.x;
    const int n0 = blockIdx.x * 64;
    const int c0 = blockIdx.y * 64;
    const int b  = blockIdx.z;
    {
        const int ci = tid >> 2, ng = tid & 3;
        const float* xs = x + (size_t)b*1048576 + (size_t)(c0+ci)*4096 + n0 + ng*16;
        #pragma unroll
        for (int k=0;k<4;++k){
            float4 v = *(const float4*)(xs + k*4);
            *(float4*)&xt[ci*68 + ng*16 + k*4] = v;
        }
    }
    __syncthreads();
    const int nr = tid >> 2, cg = tid & 3;
    const int n = n0 + nr;
    unsigned short* dstrow = XT + (size_t)b*XT_BSTRIDE + (size_t)n*256;
    #pragma unroll
    for (int t2=0;t2<2;++t2){
        s16x8 pk;
        #pragma unroll
        for (int j=0;j<8;++j){
            int c = cg*16 + t2*8 + j;
            pk[j] = (short)f2bf(xt[c*68 + nr]);
        }
        int blk = (((c0>>3) + cg*2 + t2) ^ (n & 7));
        *(s16x8*)(dstrow + blk*8) = pk;
    }
}

// ------------- prep: wqkv f32 -> bf16 ---------------------------------------
__global__ __launch_bounds__(256)
void wprep_kernel(const float* __restrict__ w, unsigned short* __restrict__ wb)
{
    int i = (blockIdx.x*256 + threadIdx.x) * 8;    // 393216 elems, grid 192
    float4 a = *(const float4*)(w + i);
    float4 b = *(const float4*)(w + i + 4);
    s16x8 pk;
    pk[0]=(short)f2bf(a.x); pk[1]=(short)f2bf(a.y); pk[2]=(short)f2bf(a.z); pk[3]=(short)f2bf(a.w);
    pk[4]=(short)f2bf(b.x); pk[5]=(short)f2bf(b.y); pk[6]=(short)f2bf(b.z); pk[7]=(short)f2bf(b.w);
    *(s16x8*)(wb + i) = pk;
}

// ------------- kernel A: KV MFMA GEMM + exp + partial context ---------------
// grid (4 segs, 128 bh), 256 thr (4 waves). LDS: xtile 32768 + kv 18432 = 51200
__global__ __launch_bounds__(256,2)
void kvctx_kernel(const unsigned short* __restrict__ XT, const unsigned short* __restrict__ wb,
                  float* __restrict__ Cp, float* __restrict__ Zp)
{
    extern __shared__ char smraw[];
    unsigned short* xtile = (unsigned short*)smraw;            // [64][256]
    unsigned short* kv    = (unsigned short*)(smraw + 32768);  // [128][72]

    const int tid = threadIdx.x;
    const int w = tid >> 6, lane = tid & 63;
    const int l15 = lane & 15, q = lane >> 4;
    const int seg = blockIdx.x;
    const int bh  = blockIdx.y;
    const int b = bh >> 3, h = bh & 7;

    // persistent W fragments: wave w owns KV rows w*32..w*32+31
    s16x8 aW[2][8];
    #pragma unroll
    for (int mf=0;mf<2;++mf){
        int rl = w*32 + mf*16 + l15;
        int grow = (rl < 64) ? (512 + h*64 + rl) : (1024 + h*64 + (rl-64));
        const unsigned short* wr = wb + (size_t)grow*256 + q*8;
        #pragma unroll
        for (int kc=0;kc<8;++kc)
            aW[mf][kc] = *(const s16x8*)(wr + kc*32);
    }

    f32x4 ctxacc[4];
    #pragma unroll
    for (int ef=0;ef<4;++ef) ctxacc[ef] = (f32x4){0.f,0.f,0.f,0.f};
    float zacc[8];
    #pragma unroll
    for (int i=0;i<8;++i) zacc[i]=0.f;

    const unsigned short* gsrc0 = XT + (size_t)b*XT_BSTRIDE + (size_t)(seg*1024)*256;

    {   // stage chunk 0
        const unsigned short* gs = gsrc0 + w*4096 + lane*8;
        #pragma unroll
        for (int j=0;j<8;++j)
            gload_lds16(gs + j*512, &xtile[w*4096 + j*512]);
    }
    __syncthreads();

    #pragma unroll 1
    for (int t=0;t<16;++t){
        // ---- KV GEMM (128 x 64 tile)
        f32x4 acc[2][4];
        #pragma unroll
        for (int mf=0;mf<2;++mf)
            #pragma unroll
            for (int nf=0;nf<4;++nf) acc[mf][nf]=(f32x4){0.f,0.f,0.f,0.f};
        #pragma unroll
        for (int kc=0;kc<8;++kc){
            s16x8 bf[4];
            #pragma unroll
            for (int nf=0;nf<4;++nf){
                int nl = nf*16 + l15;
                int blk = (kc*4 + q) ^ (nl & 7);
                bf[nf] = *(const s16x8*)&xtile[nl*256 + blk*8];
            }
            #pragma unroll
            for (int mf=0;mf<2;++mf)
                #pragma unroll
                for (int nf=0;nf<4;++nf)
                    acc[mf][nf] = MFMA(aW[mf][kc], bf[nf], acc[mf][nf]);
        }
        // ---- exp (K waves) + write KV tile to LDS [row][72]
        #pragma unroll
        for (int mf=0;mf<2;++mf){
            int row = w*32 + mf*16 + q*4;
            #pragma unroll
            for (int nf=0;nf<4;++nf){
                int col = nf*16 + l15;
                #pragma unroll
                for (int r=0;r<4;++r){
                    float v = acc[mf][nf][r];
                    if (w < 2){
                        v = __expf(v);
                        unsigned short bv = f2bf(v);
                        zacc[mf*4+r] += bf2f(bv);
                        kv[(row+r)*72 + col] = bv;
                    } else {
                        kv[(row+r)*72 + col] = f2bf(v);
                    }
                }
            }
        }
        __syncthreads();
        if (t < 15){   // prefetch next X tile, overlapped with ctx GEMM
            const unsigned short* gs = gsrc0 + (t+1)*16384 + w*4096 + lane*8;
            #pragma unroll
            for (int j=0;j<8;++j)
                gload_lds16(gs + j*512, &xtile[w*4096 + j*512]);
        }
        // ---- ctx GEMM: ctx[d,e] += expK[d,n] * V[e,n]
        #pragma unroll
        for (int kf=0;kf<2;++kf){
            s16x8 aC = *(const s16x8*)&kv[(w*16 + l15)*72 + kf*32 + q*8];
            #pragma unroll
            for (int ef=0;ef<4;++ef){
                s16x8 bC = *(const s16x8*)&kv[(64 + ef*16 + l15)*72 + kf*32 + q*8];
                ctxacc[ef] = MFMA(aC, bC, ctxacc[ef]);
            }
        }
        __syncthreads();
    }

    float* cpb = Cp + (size_t)(bh*4 + seg)*4096;
    #pragma unroll
    for (int ef=0;ef<4;++ef)
        #pragma unroll
        for (int r=0;r<4;++r){
            int d = w*16 + q*4 + r;
            cpb[d*64 + ef*16 + l15] = ctxacc[ef][r];
        }
    if (w < 2){
        #pragma unroll
        for (int i=0;i<8;++i){
            #pragma unroll
            for (int off=1; off<16; off<<=1)
                zacc[i] += __shfl_xor(zacc[i], off, 64);
        }
        if (l15 == 0){
            float* zpb = Zp + (size_t)(bh*4 + seg)*64;
            #pragma unroll
            for (int mf=0;mf<2;++mf)
                #pragma unroll
                for (int r=0;r<4;++r)
                    zpb[w*32 + mf*16 + q*4 + r] = zacc[mf*4+r];
        }
    }
}

// ------------- kernel B0: reduce partials, normalize ------------------------
__global__ __launch_bounds__(256)
void bctx_kernel(const float* __restrict__ Cp, const float* __restrict__ Zp,
                 float* __restrict__ ctx)
{
    int gid = blockIdx.x*256 + threadIdx.x;    // 524288 total
    int bh = gid >> 12, r = gid & 4095, d = r >> 6;
    float cs = 0.f, zs = 0.f;
    #pragma unroll
    for (int s=0;s<4;++s){
        cs += Cp[(size_t)(bh*4+s)*4096 + r];
        zs += Zp[(bh*4+s)*64 + d];
    }
    ctx[(size_t)bh*4096 + r] = cs / (zs * 4096.f);
}

// ------------- kernel B1: U = 0.125 * W_out ctx^T (per head), bf16 out ------
// grid (8, 16), 256 thr; LDS dyn 83200 B
__global__ __launch_bounds__(256)
void uprep_kernel(const float* __restrict__ wout, const float* __restrict__ ctx,
                  unsigned short* __restrict__ U)
{
    extern __shared__ char smraw[];
    float* wl = (float*)smraw;                  // [256][65]
    float* cl = (float*)(smraw + 66560);        // [64][65]
    const int h = blockIdx.x, b = blockIdx.y, tid = threadIdx.x;
    {
        const float* ws = wout + (size_t)tid*512 + h*64;
        #pragma unroll
        for (int j=0;j<16;++j){
            float4 v = *(const float4*)(ws + j*4);
            wl[tid*65 + j*4+0]=v.x; wl[tid*65 + j*4+1]=v.y;
            wl[tid*65 + j*4+2]=v.z; wl[tid*65 + j*4+3]=v.w;
        }
    }
    {
        const float* cs = ctx + (size_t)b*32768 + h*4096 + tid*16;
        int d = tid >> 2, e0 = (tid & 3)*16;
        #pragma unroll
        for (int j=0;j<4;++j){
            float4 v = *(const float4*)(cs + j*4);
            cl[d*65 + e0 + j*4+0]=v.x; cl[d*65 + e0 + j*4+1]=v.y;
            cl[d*65 + e0 + j*4+2]=v.z; cl[d*65 + e0 + j*4+3]=v.w;
        }
    }
    __syncthreads();
    const int d = tid & 63, og = tid >> 6;
    unsigned short* ub = U + (size_t)b*131072;
    #pragma unroll 1
    for (int k=0;k<64;++k){
        int o = og*64 + k;
        float s = 0.f;
        #pragma unroll
        for (int e=0;e<64;++e) s += wl[o*65+e]*cl[d*65+e];
        ub[(size_t)o*512 + h*64 + d] = f2bf(s * 0.125f);
    }
}

// ------------- kernel C: q MFMA -> softmax_d -> U MFMA -> bias -> LN --------
// grid (64 ntiles, 16 b), 256 thr. LDS dyn 70656 B
__global__ __launch_bounds__(256,2)
void qout_kernel(const unsigned short* __restrict__ XT, const unsigned short* __restrict__ wb,
                 const unsigned short* __restrict__ U, const float* __restrict__ bout,
                 const float* __restrict__ gg, float* __restrict__ out)
{
    extern __shared__ char smraw[];
    unsigned short* xtile = (unsigned short*)smraw;       // [64][256] (phase 1)
    unsigned short* qsm   = (unsigned short*)smraw;       // [64] rows, stride 520
    float* red = (float*)(smraw + 66560);                 // [256][2]
    float* bl  = (float*)(smraw + 68608);                 // [256]
    float* gl  = (float*)(smraw + 69632);                 // [256]

    const int tid = threadIdx.x;
    const int w = tid >> 6, lane = tid & 63, l15 = lane & 15, q = lane >> 4;
    const int b = blockIdx.y;
    const int n0 = blockIdx.x * 64;

    bl[tid] = bout[tid];
    gl[tid] = gg[tid];
    {
        const unsigned short* gs = XT + (size_t)b*XT_BSTRIDE + (size_t)n0*256 + w*4096 + lane*8;
        #pragma unroll
        for (int j=0;j<8;++j)
            gload_lds16(gs + j*512, &xtile[w*4096 + j*512]);
    }
    __syncthreads();

    // ---- q GEMM: wave w owns q rows w*128..+127
    f32x4 acc[8][4];
    #pragma unroll
    for (int mf=0;mf<8;++mf)
        #pragma unroll
        for (int nf=0;nf<4;++nf) acc[mf][nf]=(f32x4){0.f,0.f,0.f,0.f};

    #pragma unroll 1
    for (int kc=0;kc<8;++kc){
        s16x8 av[8];
        #pragma unroll
        for (int mf=0;mf<8;++mf){
            int grow = w*128 + mf*16 + l15;
            av[mf] = *(const s16x8*)(wb + (size_t)grow*256 + kc*32 + q*8);
        }
        s16x8 bf[4];
        #pragma unroll
        for (int nf=0;nf<4;++nf){
            int nl = nf*16 + l15;
            int blk = (kc*4 + q) ^ (nl & 7);
            bf[nf] = *(const s16x8*)&xtile[nl*256 + blk*8];
        }
        #pragma unroll
        for (int mf=0;mf<8;++mf)
            #pragma unroll
            for (int nf=0;nf<4;++nf)
                acc[mf][nf] = MFMA(av[mf], bf[nf], acc[mf][nf]);
    }

    // ---- softmax over d, per head per column (scale folded into U)
    #pragma unroll
    for (int hh=0;hh<2;++hh){
        #pragma unroll
        for (int nf=0;nf<4;++nf){
            float m = -1e30f;
            #pragma unroll
            for (int mf=0;mf<4;++mf)
                #pragma unroll
                for (int r=0;r<4;++r)
                    m = fmaxf(m, acc[hh*4+mf][nf][r]);
            m = fmaxf(m, __shfl_xor(m, 16, 64));
            m = fmaxf(m, __shfl_xor(m, 32, 64));
            float s = 0.f;
            #pragma unroll
            for (int mf=0;mf<4;++mf)
                #pragma unroll
                for (int r=0;r<4;++r){
                    float e = __expf(acc[hh*4+mf][nf][r] - m);
                    acc[hh*4+mf][nf][r] = e;
                    s += e;
                }
            s += __shfl_xor(s, 16, 64);
            s += __shfl_xor(s, 32, 64);
            float rs = 1.f / s;
            #pragma unroll
            for (int mf=0;mf<4;++mf)
                #pragma unroll
                for (int r=0;r<4;++r)
                    acc[hh*4+mf][nf][r] *= rs;
        }
    }
    __syncthreads();    // xtile reads done
    #pragma unroll
    for (int mf=0;mf<8;++mf){
        int dbase = w*128 + mf*16 + q*4;
        #pragma unroll
        for (int nf=0;nf<4;++nf){
            int n = nf*16 + l15;
            #pragma unroll
            for (int r=0;r<4;++r)
                qsm[n*520 + dbase + r] = f2bf(acc[mf][nf][r]);
        }
    }
    __syncthreads();

    // ---- U GEMM: wave w owns out rows w*64..+63
    f32x4 yacc[4][4];
    #pragma unroll
    for (int mf=0;mf<4;++mf)
        #pragma unroll
        for (int nf=0;nf<4;++nf) yacc[mf][nf]=(f32x4){0.f,0.f,0.f,0.f};
    const unsigned short* Ub = U + (size_t)b*131072;
    #pragma unroll 1
    for (int kc=0;kc<16;++kc){
        s16x8 av[4];
        #pragma unroll
        for (int mf=0;mf<4;++mf){
            int grow = w*64 + mf*16 + l15;
            av[mf] = *(const s16x8*)(Ub + (size_t)grow*512 + kc*32 + q*8);
        }
        s16x8 bf[4];
        #pragma unroll
        for (int nf=0;nf<4;++nf){
            int n = nf*16 + l15;
            bf[nf] = *(const s16x8*)&qsm[n*520 + kc*32 + q*8];
        }
        #pragma unroll
        for (int mf=0;mf<4;++mf)
            #pragma unroll
            for (int nf=0;nf<4;++nf)
                yacc[mf][nf] = MFMA(av[mf], bf[nf], yacc[mf][nf]);
    }
    // ---- bias
    #pragma unroll
    for (int mf=0;mf<4;++mf){
        int ob = w*64 + mf*16 + q*4;
        #pragma unroll
        for (int r=0;r<4;++r){
            float bo = bl[ob + r];
            #pragma unroll
            for (int nf=0;nf<4;++nf) yacc[mf][nf][r] += bo;
        }
    }
    // ---- LayerNorm over 256 channels
    float s1[4], s2[4];
    #pragma unroll
    for (int nf=0;nf<4;++nf){ s1[nf]=0.f; s2[nf]=0.f; }
    #pragma unroll
    for (int mf=0;mf<4;++mf)
        #pragma unroll
        for (int nf=0;nf<4;++nf)
            #pragma unroll
            for (int r=0;r<4;++r){
                float v = yacc[mf][nf][r];
                s1[nf] += v; s2[nf] += v*v;
            }
    #pragma unroll
    for (int nf=0;nf<4;++nf){
        s1[nf] += __shfl_xor(s1[nf], 16, 64);
        s1[nf] += __shfl_xor(s1[nf], 32, 64);
        s2[nf] += __shfl_xor(s2[nf], 16, 64);
        s2[nf] += __shfl_xor(s2[nf], 32, 64);
    }
    if (q == 0){
        #pragma unroll
        for (int nf=0;nf<4;++nf){
            int col = nf*16 + l15;
            red[(w*64 + col)*2 + 0] = s1[nf];
            red[(w*64 + col)*2 + 1] = s2[nf];
        }
    }
    __syncthreads();
    float mean_[4], inv_[4];
    #pragma unroll
    for (int nf=0;nf<4;++nf){
        int col = nf*16 + l15;
        float S1 = red[col*2] + red[(64+col)*2] + red[(128+col)*2] + red[(192+col)*2];
        float S2 = red[col*2+1] + red[(64+col)*2+1] + red[(128+col)*2+1] + red[(192+col)*2+1];
        float mn = S1 * (1.f/256.f);
        float vr = S2 * (1.f/256.f) - mn*mn;
        mean_[nf] = mn;
        inv_[nf] = rsqrtf(vr + 1e-5f);
    }
    float* ob = out + (size_t)b*1048576 + n0;
    #pragma unroll
    for (int mf=0;mf<4;++mf){
        #pragma unroll
        for (int r=0;r<4;++r){
            int o = w*64 + mf*16 + q*4 + r;
            float gv = gl[o];
            #pragma unroll
            for (int nf=0;nf<4;++nf){
                float val = (yacc[mf][nf][r] - mean_[nf]) * inv_[nf] * gv;
                ob[(size_t)o*4096 + nf*16 + l15] = val;
            }
        }
    }
}

// ----------------------------------------------------------------------------
extern "C" void kernel_launch(void* const* d_in, const int* in_sizes, int n_in,
                              void* d_out, int out_size, void* d_ws, size_t ws_size,
                              hipStream_t stream)
{
    const float* x    = (const float*)d_in[0];
    const float* wqkv = (const float*)d_in[1];
    const float* wout = (const float*)d_in[2];
    const float* bout = (const float*)d_in[3];
    const float* g    = (const float*)d_in[4];
    float* out = (float*)d_out;

    char* wsb = (char*)d_ws;
    unsigned short* XTs = (unsigned short*)wsb;
    unsigned short* wbf = (unsigned short*)(wsb + 33554432);
    unsigned short* Ubf = (unsigned short*)(wsb + 34340864);
    float* Cp  = (float*)(wsb + 38535168);
    float* Zp  = (float*)(wsb + 46923776);
    float* ctx = (float*)(wsb + 47054848);

    hipLaunchKernelGGL(xprep_kernel, dim3(64, 4, 16), dim3(256), 0,     stream, x, XTs);
    hipLaunchKernelGGL(wprep_kernel, dim3(192),       dim3(256), 0,     stream, wqkv, wbf);
    hipLaunchKernelGGL(kvctx_kernel, dim3(4, 128),    dim3(256), 51200, stream, XTs, wbf, Cp, Zp);
    hipLaunchKernelGGL(bctx_kernel,  dim3(2048),      dim3(256), 0,     stream, Cp, Zp, ctx);
    hipLaunchKernelGGL(uprep_kernel, dim3(8, 16),     dim3(256), 83200, stream, wout, ctx, Ubf);
    hipLaunchKernelGGL(qout_kernel,  dim3(64, 16),    dim3(256), 70656, stream, XTs, wbf, Ubf, bout, g, out);
}

// Round 4
// 193.757 us; speedup vs baseline: 27.5624x; 1.0760x over previous
//
#include <hip/hip_runtime.h>
#include <cstddef>
#include <cstdint>

// LinearAttention MI355X round 4:
//  - qout: software-pipelined weight-fragment prefetch (ping-pong avA/avB) in
//    both GEMMs + s_setprio around MFMA clusters (L2 latency was unhidden:
//    MfmaUtil 14.7%, VALUBusy 20%, dur 91.5us vs ~20us floor).
//  - bctx+uprep fused into ctxu_kernel (one less launch, no ctx round-trip).
//
// y = LN( U_b @ softmax_d(W_q X_b) + b_out ),  U_b = 0.125 * W_out ctx_b^T (per head)
// ctx_b[h,d,e] = (sum_n exp(K[d,n]) V[e,n]) / (Z_d * 4096)
//
// ws layout (bytes):
//   XTs  (bf16, swizzled [b][n][c]) : 0          .. 33,554,432
//   wbf  (bf16 wqkv)                : 33,554,432 .. 34,340,864
//   Ubf  (bf16 U)                   : 34,340,864 .. 38,535,168
//   Cp   (f32 ctx partials)         : 38,535,168 .. 46,923,776
//   Zp   (f32 Z partials)           : 46,923,776 .. 47,054,848

typedef __attribute__((ext_vector_type(8))) short s16x8;
typedef __attribute__((ext_vector_type(4))) float f32x4;

#define MFMA(a,b,c) __builtin_amdgcn_mfma_f32_16x16x32_bf16(a,b,c,0,0,0)

#define XT_BSTRIDE 1048576   // shorts per batch: 4096 tokens * 256 ch

__device__ __forceinline__ unsigned short f2bf(float f){
    union { float f; unsigned int u; } v; v.f = f;
    unsigned int u = v.u;
    unsigned int r = (u + 0x7FFFu + ((u >> 16) & 1u)) >> 16;   // RNE
    return (unsigned short)r;
}
__device__ __forceinline__ float bf2f(unsigned short b){
    union { unsigned int u; float f; } v; v.u = ((unsigned int)b) << 16;
    return v.f;
}
__device__ __forceinline__ void gload_lds16(const void* g, void* l){
    __builtin_amdgcn_global_load_lds(
        (const __attribute__((address_space(1))) unsigned int*)g,
        (__attribute__((address_space(3))) unsigned int*)l, 16, 0, 0);
}

// ------------- prep: x [b][c][n] f32 -> XT [b][n][c] bf16, block-swizzled ----
__global__ __launch_bounds__(256)
void xprep_kernel(const float* __restrict__ x, unsigned short* __restrict__ XT)
{
    __shared__ float xt[64*68];
    const int tid = threadIdx.x;
    const int n0 = blockIdx.x * 64;
    const int c0 = blockIdx.y * 64;
    const int b  = blockIdx.z;
    {
        const int ci = tid >> 2, ng = tid & 3;
        const float* xs = x + (size_t)b*1048576 + (size_t)(c0+ci)*4096 + n0 + ng*16;
        #pragma unroll
        for (int k=0;k<4;++k){
            float4 v = *(const float4*)(xs + k*4);
            *(float4*)&xt[ci*68 + ng*16 + k*4] = v;
        }
    }
    __syncthreads();
    const int nr = tid >> 2, cg = tid & 3;
    const int n = n0 + nr;
    unsigned short* dstrow = XT + (size_t)b*XT_BSTRIDE + (size_t)n*256;
    #pragma unroll
    for (int t2=0;t2<2;++t2){
        s16x8 pk;
        #pragma unroll
        for (int j=0;j<8;++j){
            int c = cg*16 + t2*8 + j;
            pk[j] = (short)f2bf(xt[c*68 + nr]);
        }
        int blk = (((c0>>3) + cg*2 + t2) ^ (n & 7));
        *(s16x8*)(dstrow + blk*8) = pk;
    }
}

// ------------- prep: wqkv f32 -> bf16 ---------------------------------------
__global__ __launch_bounds__(256)
void wprep_kernel(const float* __restrict__ w, unsigned short* __restrict__ wb)
{
    int i = (blockIdx.x*256 + threadIdx.x) * 8;    // 393216 elems, grid 192
    float4 a = *(const float4*)(w + i);
    float4 b = *(const float4*)(w + i + 4);
    s16x8 pk;
    pk[0]=(short)f2bf(a.x); pk[1]=(short)f2bf(a.y); pk[2]=(short)f2bf(a.z); pk[3]=(short)f2bf(a.w);
    pk[4]=(short)f2bf(b.x); pk[5]=(short)f2bf(b.y); pk[6]=(short)f2bf(b.z); pk[7]=(short)f2bf(b.w);
    *(s16x8*)(wb + i) = pk;
}

// ------------- kernel A: KV MFMA GEMM + exp + partial context ---------------
// grid (4 segs, 128 bh), 256 thr (4 waves). LDS: xtile 32768 + kv 18432 = 51200
__global__ __launch_bounds__(256,2)
void kvctx_kernel(const unsigned short* __restrict__ XT, const unsigned short* __restrict__ wb,
                  float* __restrict__ Cp, float* __restrict__ Zp)
{
    extern __shared__ char smraw[];
    unsigned short* xtile = (unsigned short*)smraw;            // [64][256]
    unsigned short* kv    = (unsigned short*)(smraw + 32768);  // [128][72]

    const int tid = threadIdx.x;
    const int w = tid >> 6, lane = tid & 63;
    const int l15 = lane & 15, q = lane >> 4;
    const int seg = blockIdx.x;
    const int bh  = blockIdx.y;
    const int b = bh >> 3, h = bh & 7;

    // persistent W fragments: wave w owns KV rows w*32..w*32+31
    s16x8 aW[2][8];
    #pragma unroll
    for (int mf=0;mf<2;++mf){
        int rl = w*32 + mf*16 + l15;
        int grow = (rl < 64) ? (512 + h*64 + rl) : (1024 + h*64 + (rl-64));
        const unsigned short* wr = wb + (size_t)grow*256 + q*8;
        #pragma unroll
        for (int kc=0;kc<8;++kc)
            aW[mf][kc] = *(const s16x8*)(wr + kc*32);
    }

    f32x4 ctxacc[4];
    #pragma unroll
    for (int ef=0;ef<4;++ef) ctxacc[ef] = (f32x4){0.f,0.f,0.f,0.f};
    float zacc[8];
    #pragma unroll
    for (int i=0;i<8;++i) zacc[i]=0.f;

    const unsigned short* gsrc0 = XT + (size_t)b*XT_BSTRIDE + (size_t)(seg*1024)*256;

    {   // stage chunk 0
        const unsigned short* gs = gsrc0 + w*4096 + lane*8;
        #pragma unroll
        for (int j=0;j<8;++j)
            gload_lds16(gs + j*512, &xtile[w*4096 + j*512]);
    }
    __syncthreads();

    #pragma unroll 1
    for (int t=0;t<16;++t){
        // ---- KV GEMM (128 x 64 tile)
        f32x4 acc[2][4];
        #pragma unroll
        for (int mf=0;mf<2;++mf)
            #pragma unroll
            for (int nf=0;nf<4;++nf) acc[mf][nf]=(f32x4){0.f,0.f,0.f,0.f};
        #pragma unroll
        for (int kc=0;kc<8;++kc){
            s16x8 bf[4];
            #pragma unroll
            for (int nf=0;nf<4;++nf){
                int nl = nf*16 + l15;
                int blk = (kc*4 + q) ^ (nl & 7);
                bf[nf] = *(const s16x8*)&xtile[nl*256 + blk*8];
            }
            #pragma unroll
            for (int mf=0;mf<2;++mf)
                #pragma unroll
                for (int nf=0;nf<4;++nf)
                    acc[mf][nf] = MFMA(aW[mf][kc], bf[nf], acc[mf][nf]);
        }
        // ---- exp (K waves) + write KV tile to LDS [row][72]
        #pragma unroll
        for (int mf=0;mf<2;++mf){
            int row = w*32 + mf*16 + q*4;
            #pragma unroll
            for (int nf=0;nf<4;++nf){
                int col = nf*16 + l15;
                #pragma unroll
                for (int r=0;r<4;++r){
                    float v = acc[mf][nf][r];
                    if (w < 2){
                        v = __expf(v);
                        unsigned short bv = f2bf(v);
                        zacc[mf*4+r] += bf2f(bv);
                        kv[(row+r)*72 + col] = bv;
                    } else {
                        kv[(row+r)*72 + col] = f2bf(v);
                    }
                }
            }
        }
        __syncthreads();
        if (t < 15){   // prefetch next X tile, overlapped with ctx GEMM
            const unsigned short* gs = gsrc0 + (t+1)*16384 + w*4096 + lane*8;
            #pragma unroll
            for (int j=0;j<8;++j)
                gload_lds16(gs + j*512, &xtile[w*4096 + j*512]);
        }
        // ---- ctx GEMM: ctx[d,e] += expK[d,n] * V[e,n]
        #pragma unroll
        for (int kf=0;kf<2;++kf){
            s16x8 aC = *(const s16x8*)&kv[(w*16 + l15)*72 + kf*32 + q*8];
            #pragma unroll
            for (int ef=0;ef<4;++ef){
                s16x8 bC = *(const s16x8*)&kv[(64 + ef*16 + l15)*72 + kf*32 + q*8];
                ctxacc[ef] = MFMA(aC, bC, ctxacc[ef]);
            }
        }
        __syncthreads();
    }

    float* cpb = Cp + (size_t)(bh*4 + seg)*4096;
    #pragma unroll
    for (int ef=0;ef<4;++ef)
        #pragma unroll
        for (int r=0;r<4;++r){
            int d = w*16 + q*4 + r;
            cpb[d*64 + ef*16 + l15] = ctxacc[ef][r];
        }
    if (w < 2){
        #pragma unroll
        for (int i=0;i<8;++i){
            #pragma unroll
            for (int off=1; off<16; off<<=1)
                zacc[i] += __shfl_xor(zacc[i], off, 64);
        }
        if (l15 == 0){
            float* zpb = Zp + (size_t)(bh*4 + seg)*64;
            #pragma unroll
            for (int mf=0;mf<2;++mf)
                #pragma unroll
                for (int r=0;r<4;++r)
                    zpb[w*32 + mf*16 + q*4 + r] = zacc[mf*4+r];
        }
    }
}

// ------------- kernel B: reduce Cp/Zp + U = 0.125 * W_out ctx^T -------------
// grid (8 h, 16 b), 256 thr; LDS dyn 83456 B
__global__ __launch_bounds__(256)
void ctxu_kernel(const float* __restrict__ Cp, const float* __restrict__ Zp,
                 const float* __restrict__ wout, unsigned short* __restrict__ U)
{
    extern __shared__ char smraw[];
    float* wl = (float*)smraw;                  // [256][65]
    float* cl = (float*)(smraw + 66560);        // [64][65]
    float* zi = (float*)(smraw + 83200);        // [64]
    const int h = blockIdx.x, b = blockIdx.y, tid = threadIdx.x;
    const int bh = b*8 + h;
    {
        const float* wsrc = wout + (size_t)tid*512 + h*64;
        #pragma unroll
        for (int j=0;j<16;++j){
            float4 v = *(const float4*)(wsrc + j*4);
            wl[tid*65 + j*4+0]=v.x; wl[tid*65 + j*4+1]=v.y;
            wl[tid*65 + j*4+2]=v.z; wl[tid*65 + j*4+3]=v.w;
        }
    }
    if (tid < 64){
        float zs = 0.f;
        #pragma unroll
        for (int s=0;s<4;++s) zs += Zp[(bh*4+s)*64 + tid];
        zi[tid] = 1.f / (zs * 4096.f);
    }
    __syncthreads();
    {
        const int d = tid >> 2, e0 = (tid & 3) * 16;
        const float* cb = Cp + (size_t)(bh*4)*4096 + d*64 + e0;
        float v[16];
        #pragma unroll
        for (int j=0;j<16;++j) v[j]=0.f;
        #pragma unroll
        for (int s=0;s<4;++s){
            #pragma unroll
            for (int j4=0;j4<4;++j4){
                float4 t = *(const float4*)(cb + (size_t)s*4096 + j4*4);
                v[j4*4+0]+=t.x; v[j4*4+1]+=t.y; v[j4*4+2]+=t.z; v[j4*4+3]+=t.w;
            }
        }
        float zv = zi[d];
        #pragma unroll
        for (int j=0;j<16;++j) cl[d*65 + e0 + j] = v[j] * zv;
    }
    __syncthreads();
    const int d = tid & 63, og = tid >> 6;
    unsigned short* ub = U + (size_t)b*131072;
    #pragma unroll 1
    for (int k=0;k<64;++k){
        int o = og*64 + k;
        float s = 0.f;
        #pragma unroll
        for (int e=0;e<64;++e) s += wl[o*65+e]*cl[d*65+e];
        ub[(size_t)o*512 + h*64 + d] = f2bf(s * 0.125f);
    }
}

// ------------- kernel C: q MFMA -> softmax_d -> U MFMA -> bias -> LN --------
// grid (64 ntiles, 16 b), 256 thr. LDS dyn 70656 B
__global__ __launch_bounds__(256,2)
void qout_kernel(const unsigned short* __restrict__ XT, const unsigned short* __restrict__ wb,
                 const unsigned short* __restrict__ U, const float* __restrict__ bout,
                 const float* __restrict__ gg, float* __restrict__ out)
{
    extern __shared__ char smraw[];
    unsigned short* xtile = (unsigned short*)smraw;       // [64][256] (phase 1)
    unsigned short* qsm   = (unsigned short*)smraw;       // [64] rows, stride 520
    float* red = (float*)(smraw + 66560);                 // [256][2]
    float* bl  = (float*)(smraw + 68608);                 // [256]
    float* gl  = (float*)(smraw + 69632);                 // [256]

    const int tid = threadIdx.x;
    const int w = tid >> 6, lane = tid & 63, l15 = lane & 15, q = lane >> 4;
    const int b = blockIdx.y;
    const int n0 = blockIdx.x * 64;

    bl[tid] = bout[tid];
    gl[tid] = gg[tid];
    {
        const unsigned short* gs = XT + (size_t)b*XT_BSTRIDE + (size_t)n0*256 + w*4096 + lane*8;
        #pragma unroll
        for (int j=0;j<8;++j)
            gload_lds16(gs + j*512, &xtile[w*4096 + j*512]);
    }
    __syncthreads();

    // ---- q GEMM: wave w owns q rows w*128..+127, pipelined weight prefetch
    f32x4 acc[8][4];
    #pragma unroll
    for (int mf=0;mf<8;++mf)
        #pragma unroll
        for (int nf=0;nf<4;++nf) acc[mf][nf]=(f32x4){0.f,0.f,0.f,0.f};

    const unsigned short* wq = wb + (size_t)(w*128 + l15)*256 + q*8;
    s16x8 avA[8], avB[8];
    #pragma unroll
    for (int mf=0;mf<8;++mf) avA[mf] = *(const s16x8*)(wq + (size_t)mf*16*256);

    #pragma unroll 1
    for (int kc=0; kc<8; kc+=2){
        #pragma unroll
        for (int mf=0;mf<8;++mf) avB[mf] = *(const s16x8*)(wq + (size_t)mf*16*256 + (kc+1)*32);
        {
            s16x8 bf[4];
            #pragma unroll
            for (int nf=0;nf<4;++nf){
                int nl = nf*16 + l15;
                int blk = (kc*4 + q) ^ (nl & 7);
                bf[nf] = *(const s16x8*)&xtile[nl*256 + blk*8];
            }
            __builtin_amdgcn_s_setprio(1);
            #pragma unroll
            for (int mf=0;mf<8;++mf)
                #pragma unroll
                for (int nf=0;nf<4;++nf)
                    acc[mf][nf] = MFMA(avA[mf], bf[nf], acc[mf][nf]);
            __builtin_amdgcn_s_setprio(0);
        }
        if (kc+2 < 8){
            #pragma unroll
            for (int mf=0;mf<8;++mf) avA[mf] = *(const s16x8*)(wq + (size_t)mf*16*256 + (kc+2)*32);
        }
        {
            s16x8 bf[4];
            #pragma unroll
            for (int nf=0;nf<4;++nf){
                int nl = nf*16 + l15;
                int blk = ((kc+1)*4 + q) ^ (nl & 7);
                bf[nf] = *(const s16x8*)&xtile[nl*256 + blk*8];
            }
            __builtin_amdgcn_s_setprio(1);
            #pragma unroll
            for (int mf=0;mf<8;++mf)
                #pragma unroll
                for (int nf=0;nf<4;++nf)
                    acc[mf][nf] = MFMA(avB[mf], bf[nf], acc[mf][nf]);
            __builtin_amdgcn_s_setprio(0);
        }
    }

    // ---- softmax over d, per head per column (scale folded into U)
    #pragma unroll
    for (int hh=0;hh<2;++hh){
        #pragma unroll
        for (int nf=0;nf<4;++nf){
            float m = -1e30f;
            #pragma unroll
            for (int mf=0;mf<4;++mf)
                #pragma unroll
                for (int r=0;r<4;++r)
                    m = fmaxf(m, acc[hh*4+mf][nf][r]);
            m = fmaxf(m, __shfl_xor(m, 16, 64));
            m = fmaxf(m, __shfl_xor(m, 32, 64));
            float s = 0.f;
            #pragma unroll
            for (int mf=0;mf<4;++mf)
                #pragma unroll
                for (int r=0;r<4;++r){
                    float e = __expf(acc[hh*4+mf][nf][r] - m);
                    acc[hh*4+mf][nf][r] = e;
                    s += e;
                }
            s += __shfl_xor(s, 16, 64);
            s += __shfl_xor(s, 32, 64);
            float rs = 1.f / s;
            #pragma unroll
            for (int mf=0;mf<4;++mf)
                #pragma unroll
                for (int r=0;r<4;++r)
                    acc[hh*4+mf][nf][r] *= rs;
        }
    }
    __syncthreads();    // xtile reads done
    #pragma unroll
    for (int mf=0;mf<8;++mf){
        int dbase = w*128 + mf*16 + q*4;
        #pragma unroll
        for (int nf=0;nf<4;++nf){
            int n = nf*16 + l15;
            #pragma unroll
            for (int r=0;r<4;++r)
                qsm[n*520 + dbase + r] = f2bf(acc[mf][nf][r]);
        }
    }
    __syncthreads();

    // ---- U GEMM: wave w owns out rows w*64..+63, pipelined weight prefetch
    f32x4 yacc[4][4];
    #pragma unroll
    for (int mf=0;mf<4;++mf)
        #pragma unroll
        for (int nf=0;nf<4;++nf) yacc[mf][nf]=(f32x4){0.f,0.f,0.f,0.f};
    const unsigned short* Ub = U + (size_t)b*131072 + (size_t)(w*64 + l15)*512 + q*8;
    s16x8 uvA[4], uvB[4];
    #pragma unroll
    for (int mf=0;mf<4;++mf) uvA[mf] = *(const s16x8*)(Ub + (size_t)mf*16*512);

    #pragma unroll 1
    for (int kc=0; kc<16; kc+=2){
        #pragma unroll
        for (int mf=0;mf<4;++mf) uvB[mf] = *(const s16x8*)(Ub + (size_t)mf*16*512 + (kc+1)*32);
        {
            s16x8 bf[4];
            #pragma unroll
            for (int nf=0;nf<4;++nf){
                int n = nf*16 + l15;
                bf[nf] = *(const s16x8*)&qsm[n*520 + kc*32 + q*8];
            }
            __builtin_amdgcn_s_setprio(1);
            #pragma unroll
            for (int mf=0;mf<4;++mf)
                #pragma unroll
                for (int nf=0;nf<4;++nf)
                    yacc[mf][nf] = MFMA(uvA[mf], bf[nf], yacc[mf][nf]);
            __builtin_amdgcn_s_setprio(0);
        }
        if (kc+2 < 16){
            #pragma unroll
            for (int mf=0;mf<4;++mf) uvA[mf] = *(const s16x8*)(Ub + (size_t)mf*16*512 + (kc+2)*32);
        }
        {
            s16x8 bf[4];
            #pragma unroll
            for (int nf=0;nf<4;++nf){
                int n = nf*16 + l15;
                bf[nf] = *(const s16x8*)&qsm[n*520 + (kc+1)*32 + q*8];
            }
            __builtin_amdgcn_s_setprio(1);
            #pragma unroll
            for (int mf=0;mf<4;++mf)
                #pragma unroll
                for (int nf=0;nf<4;++nf)
                    yacc[mf][nf] = MFMA(uvB[mf], bf[nf], yacc[mf][nf]);
            __builtin_amdgcn_s_setprio(0);
        }
    }
    // ---- bias
    #pragma unroll
    for (int mf=0;mf<4;++mf){
        int ob = w*64 + mf*16 + q*4;
        #pragma unroll
        for (int r=0;r<4;++r){
            float bo = bl[ob + r];
            #pragma unroll
            for (int nf=0;nf<4;++nf) yacc[mf][nf][r] += bo;
        }
    }
    // ---- LayerNorm over 256 channels
    float s1[4], s2[4];
    #pragma unroll
    for (int nf=0;nf<4;++nf){ s1[nf]=0.f; s2[nf]=0.f; }
    #pragma unroll
    for (int mf=0;mf<4;++mf)
        #pragma unroll
        for (int nf=0;nf<4;++nf)
            #pragma unroll
            for (int r=0;r<4;++r){
                float v = yacc[mf][nf][r];
                s1[nf] += v; s2[nf] += v*v;
            }
    #pragma unroll
    for (int nf=0;nf<4;++nf){
        s1[nf] += __shfl_xor(s1[nf], 16, 64);
        s1[nf] += __shfl_xor(s1[nf], 32, 64);
        s2[nf] += __shfl_xor(s2[nf], 16, 64);
        s2[nf] += __shfl_xor(s2[nf], 32, 64);
    }
    if (q == 0){
        #pragma unroll
        for (int nf=0;nf<4;++nf){
            int col = nf*16 + l15;
            red[(w*64 + col)*2 + 0] = s1[nf];
            red[(w*64 + col)*2 + 1] = s2[nf];
        }
    }
    __syncthreads();
    float mean_[4], inv_[4];
    #pragma unroll
    for (int nf=0;nf<4;++nf){
        int col = nf*16 + l15;
        float S1 = red[col*2] + red[(64+col)*2] + red[(128+col)*2] + red[(192+col)*2];
        float S2 = red[col*2+1] + red[(64+col)*2+1] + red[(128+col)*2+1] + red[(192+col)*2+1];
        float mn = S1 * (1.f/256.f);
        float vr = S2 * (1.f/256.f) - mn*mn;
        mean_[nf] = mn;
        inv_[nf] = rsqrtf(vr + 1e-5f);
    }
    float* ob = out + (size_t)b*1048576 + n0;
    #pragma unroll
    for (int mf=0;mf<4;++mf){
        #pragma unroll
        for (int r=0;r<4;++r){
            int o = w*64 + mf*16 + q*4 + r;
            float gv = gl[o];
            #pragma unroll
            for (int nf=0;nf<4;++nf){
                float val = (yacc[mf][nf][r] - mean_[nf]) * inv_[nf] * gv;
                ob[(size_t)o*4096 + nf*16 + l15] = val;
            }
        }
    }
}

// ----------------------------------------------------------------------------
extern "C" void kernel_launch(void* const* d_in, const int* in_sizes, int n_in,
                              void* d_out, int out_size, void* d_ws, size_t ws_size,
                              hipStream_t stream)
{
    const float* x    = (const float*)d_in[0];
    const float* wqkv = (const float*)d_in[1];
    const float* wout = (const float*)d_in[2];
    const float* bout = (const float*)d_in[3];
    const float* g    = (const float*)d_in[4];
    float* out = (float*)d_out;

    char* wsb = (char*)d_ws;
    unsigned short* XTs = (unsigned short*)wsb;
    unsigned short* wbf = (unsigned short*)(wsb + 33554432);
    unsigned short* Ubf = (unsigned short*)(wsb + 34340864);
    float* Cp  = (float*)(wsb + 38535168);
    float* Zp  = (float*)(wsb + 46923776);

    hipLaunchKernelGGL(xprep_kernel, dim3(64, 4, 16), dim3(256), 0,     stream, x, XTs);
    hipLaunchKernelGGL(wprep_kernel, dim3(192),       dim3(256), 0,     stream, wqkv, wbf);
    hipLaunchKernelGGL(kvctx_kernel, dim3(4, 128),    dim3(256), 51200, stream, XTs, wbf, Cp, Zp);
    hipLaunchKernelGGL(ctxu_kernel,  dim3(8, 16),     dim3(256), 83456, stream, Cp, Zp, wout, Ubf);
    hipLaunchKernelGGL(qout_kernel,  dim3(64, 16),    dim3(256), 70656, stream, XTs, wbf, Ubf, bout, g, out);
}